// Round 4
// baseline (135.294 us; speedup 1.0000x reference)
//
#include <hip/hip_runtime.h>

#define NBINS 256
#define SLOT (6 * NBINS)   // ints per partial-histogram slot

// cs[i] = clip(-1 + i/127, -1, 1) computed exactly as the reference (fp32 ops)
__device__ __forceinline__ float csv(int i) {
    float c = -1.0f + (float)i / 127.0f;
    return fminf(fmaxf(c, -1.0f), 1.0f);
}

__device__ __forceinline__ int binof(float v) {
    v = fminf(fmaxf(v, -1.0f), 1.0f);
    int b = (int)((v + 1.0f) * 128.0f);   // trunc toward zero == astype(int32)
    return min(max(b, 0), NBINS - 1);
}

// ---------------------------------------------------------------------------
// Kernel 1: per-block private histograms -> partials[blockIdx][6][256]
// (non-atomic flush). Each thread handles groups of 12 consecutive elements
// (= 3 float4 loads) so channel indices are compile-time constants.
// Grid must be exactly NB blocks (each owns one partials slot).
// ---------------------------------------------------------------------------
__global__ __launch_bounds__(256) void hm_hist(const float* __restrict__ src,
                                               const float* __restrict__ tgt,
                                               int ngroups, int n,
                                               int* __restrict__ partials) {
    __shared__ int lh[SLOT];
    for (int i = threadIdx.x; i < SLOT; i += blockDim.x) lh[i] = 0;
    __syncthreads();

    const float4* __restrict__ s4 = (const float4*)src;
    const float4* __restrict__ t4 = (const float4*)tgt;
    const int stride = gridDim.x * blockDim.x;
    for (int g = blockIdx.x * blockDim.x + threadIdx.x; g < ngroups; g += stride) {
        int b = g * 3;   // float4 index; covers flat elements 12g .. 12g+11
        float4 s0 = s4[b], s1 = s4[b + 1], s2 = s4[b + 2];
        float4 t0 = t4[b], t1 = t4[b + 1], t2 = t4[b + 2];
        // channels of elements 12g+0..11 are 0,1,2,0,1,2,0,1,2,0,1,2
        atomicAdd(&lh[0 * NBINS + binof(s0.x)], 1);
        atomicAdd(&lh[1 * NBINS + binof(s0.y)], 1);
        atomicAdd(&lh[2 * NBINS + binof(s0.z)], 1);
        atomicAdd(&lh[0 * NBINS + binof(s0.w)], 1);
        atomicAdd(&lh[1 * NBINS + binof(s1.x)], 1);
        atomicAdd(&lh[2 * NBINS + binof(s1.y)], 1);
        atomicAdd(&lh[0 * NBINS + binof(s1.z)], 1);
        atomicAdd(&lh[1 * NBINS + binof(s1.w)], 1);
        atomicAdd(&lh[2 * NBINS + binof(s2.x)], 1);
        atomicAdd(&lh[0 * NBINS + binof(s2.y)], 1);
        atomicAdd(&lh[1 * NBINS + binof(s2.z)], 1);
        atomicAdd(&lh[2 * NBINS + binof(s2.w)], 1);

        atomicAdd(&lh[3 * NBINS + binof(t0.x)], 1);
        atomicAdd(&lh[4 * NBINS + binof(t0.y)], 1);
        atomicAdd(&lh[5 * NBINS + binof(t0.z)], 1);
        atomicAdd(&lh[3 * NBINS + binof(t0.w)], 1);
        atomicAdd(&lh[4 * NBINS + binof(t1.x)], 1);
        atomicAdd(&lh[5 * NBINS + binof(t1.y)], 1);
        atomicAdd(&lh[3 * NBINS + binof(t1.z)], 1);
        atomicAdd(&lh[4 * NBINS + binof(t1.w)], 1);
        atomicAdd(&lh[5 * NBINS + binof(t2.x)], 1);
        atomicAdd(&lh[3 * NBINS + binof(t2.y)], 1);
        atomicAdd(&lh[4 * NBINS + binof(t2.z)], 1);
        atomicAdd(&lh[5 * NBINS + binof(t2.w)], 1);
    }
    // scalar tail (n not divisible by 12)
    if (blockIdx.x == 0) {
        int base = ngroups * 12;
        int rem = n - base;
        if ((int)threadIdx.x < rem) {
            int j = base + threadIdx.x;
            int c = j % 3;
            atomicAdd(&lh[c * NBINS + binof(src[j])], 1);
            atomicAdd(&lh[(3 + c) * NBINS + binof(tgt[j])], 1);
        }
    }
    __syncthreads();

    int* dst = partials + blockIdx.x * SLOT;
    for (int i = threadIdx.x; i < SLOT; i += blockDim.x) dst[i] = lh[i];
}

// ---------------------------------------------------------------------------
// Kernel 2 (fused reduce+tables): 3 blocks (one per channel) x 1024 threads.
// 4 thread-groups of 256 reduce the NB partial slots in parallel, LDS-combine,
// then scan -> cdfs/cdft -> pxmap = _interpolate(cdftgt, cs, cdfsrc).
// ---------------------------------------------------------------------------
__global__ __launch_bounds__(1024) void hm_tables(const int* __restrict__ partials,
                                                  int NB, float pixcnt_m1,
                                                  float* __restrict__ pxmap) {
    const int c = blockIdx.x;
    const int t = threadIdx.x;
    const int grp = t >> 8;     // 0..3
    const int bin = t & 255;

    __shared__ int red[8][NBINS];          // [grp] src, [4+grp] tgt
    __shared__ int ss[NBINS], st[NBINS];
    __shared__ float cdfs[NBINS], cdft[NBINS];

    int as = 0, at = 0;
    for (int b = grp; b < NB; b += 4) {
        const int* p = partials + b * SLOT;
        as += p[c * NBINS + bin];
        at += p[(3 + c) * NBINS + bin];
    }
    red[grp][bin] = as;
    red[4 + grp][bin] = at;
    __syncthreads();

    if (t < NBINS) {
        ss[t] = red[0][t] + red[1][t] + red[2][t] + red[3][t];
        st[t] = red[4][t] + red[5][t] + red[6][t] + red[7][t];
    }
    __syncthreads();

    // Hillis-Steele inclusive scan (256 active lanes; all threads hit barriers)
    for (int off = 1; off < NBINS; off <<= 1) {
        int a = 0, b = 0;
        if (t < NBINS && t >= off) { a = ss[t - off]; b = st[t - off]; }
        __syncthreads();
        if (t < NBINS && t >= off) { ss[t] += a; st[t] += b; }
        __syncthreads();
    }

    if (t < NBINS) {
        // cdf nondecreasing -> min = cdf[0]; exact ref op order
        int mins = ss[0];
        int mint = st[0];
        cdfs[t] = (float)(ss[t] - mins) * 2.0f / pixcnt_m1 - 1.0f;
        cdft[t] = (float)(st[t] - mint) * 2.0f / pixcnt_m1 - 1.0f;
    }
    __syncthreads();

    if (t < NBINS) {
        // pxmap[t] = _interpolate(dx=cdftgt, dy=cs, x=cdfsrc[t]); first-min argmin
        float x = cdfs[t];
        int ind1 = 0;
        float best = fabsf(cdft[0] - x);
        for (int i = 1; i < NBINS; i++) {
            float d = fabsf(cdft[i] - x);
            if (d < best) { best = d; ind1 = i; }
        }
        int ind0 = max(ind1 - 1, 0);
        float x0 = cdft[ind0], x1 = cdft[ind1];
        float y0 = csv(ind0),  y1 = csv(ind1);
        float denom = x1 - x0;
        float safe = (denom == 0.0f) ? 1.0f : denom;
        float interp = y0 + (y1 - y0) * (x - x0) / safe;

        float r;
        if (x <= cdft[0])              r = csv(0);
        else if (x >= cdft[NBINS - 1]) r = csv(NBINS - 1);
        else                           r = interp;

        pxmap[c * NBINS + t] = r;
    }
}

// ---------------------------------------------------------------------------
// Kernel 3: mapped = _interpolate(dx=cs, dy=pxmap[c], x=src). 12-elem groups,
// compile-time channels, cs table in LDS (no fp32 divides for grid values).
// ---------------------------------------------------------------------------
__device__ __forceinline__ float map_one(float x, const float* __restrict__ y,
                                         const float* __restrict__ cs) {
    if (x <= -1.0f) return y[0];
    if (x >= 1.0f)  return y[NBINS - 1];
    float kf = (x + 1.0f) * 127.0f;
    int k = (int)(kf + 0.5f);
    int lo = max(k - 1, 0);
    int hi = min(k + 1, NBINS - 1);
    int ind1 = lo;
    float best = fabsf(cs[lo] - x);
    for (int j = lo + 1; j <= hi; j++) {
        float d = fabsf(cs[j] - x);
        if (d < best) { best = d; ind1 = j; }   // strict < => first-min
    }
    int ind0 = max(ind1 - 1, 0);
    float x0 = cs[ind0], x1 = cs[ind1];
    float y0 = y[ind0],  y1 = y[ind1];
    float denom = x1 - x0;
    float safe = (denom == 0.0f) ? 1.0f : denom;
    return y0 + (y1 - y0) * (x - x0) / safe;
}

__global__ __launch_bounds__(256) void hm_map(const float* __restrict__ src,
                                              const float* __restrict__ pxmap,
                                              float* __restrict__ out,
                                              int ngroups, int n) {
    __shared__ float pm[3 * NBINS];
    __shared__ float cs[NBINS];
    for (int i = threadIdx.x; i < 3 * NBINS; i += blockDim.x) pm[i] = pxmap[i];
    for (int i = threadIdx.x; i < NBINS; i += blockDim.x) cs[i] = csv(i);
    __syncthreads();

    const float4* __restrict__ s4 = (const float4*)src;
    float4* __restrict__ o4 = (float4*)out;
    const int stride = gridDim.x * blockDim.x;
    for (int g = blockIdx.x * blockDim.x + threadIdx.x; g < ngroups; g += stride) {
        int b = g * 3;
        float4 s0 = s4[b], s1 = s4[b + 1], s2 = s4[b + 2];
        float4 r0, r1, r2;
        r0.x = map_one(s0.x, &pm[0 * NBINS], cs);
        r0.y = map_one(s0.y, &pm[1 * NBINS], cs);
        r0.z = map_one(s0.z, &pm[2 * NBINS], cs);
        r0.w = map_one(s0.w, &pm[0 * NBINS], cs);
        r1.x = map_one(s1.x, &pm[1 * NBINS], cs);
        r1.y = map_one(s1.y, &pm[2 * NBINS], cs);
        r1.z = map_one(s1.z, &pm[0 * NBINS], cs);
        r1.w = map_one(s1.w, &pm[1 * NBINS], cs);
        r2.x = map_one(s2.x, &pm[2 * NBINS], cs);
        r2.y = map_one(s2.y, &pm[0 * NBINS], cs);
        r2.z = map_one(s2.z, &pm[1 * NBINS], cs);
        r2.w = map_one(s2.w, &pm[2 * NBINS], cs);
        o4[b] = r0; o4[b + 1] = r1; o4[b + 2] = r2;
    }
    // scalar tail
    if (blockIdx.x == 0) {
        int base = ngroups * 12;
        int rem = n - base;
        if ((int)threadIdx.x < rem) {
            int j = base + threadIdx.x;
            int c = j % 3;
            out[j] = map_one(src[j], &pm[c * NBINS], cs);
        }
    }
}

extern "C" void kernel_launch(void* const* d_in, const int* in_sizes, int n_in,
                              void* d_out, int out_size, void* d_ws, size_t ws_size,
                              hipStream_t stream) {
    const float* src = (const float*)d_in[0];
    const float* tgt = (const float*)d_in[1];
    float* out = (float*)d_out;

    const int n = in_sizes[0];       // H*W*3
    const int ngroups = n / 12;      // 12-element (3x float4) groups
    const int pixcnt = n / 3;        // H*W

    // ws layout: [0, 4096): pxmap (3*256 floats); [4096, ...): partials
    float* pxmap    = (float*)d_ws;
    int*   partials = (int*)((char*)d_ws + 4096);

    const int slot_bytes = SLOT * (int)sizeof(int);   // 6 KiB per slot
    int NB = 1024;                                    // 4 blocks/CU
    int need = (ngroups + 255) / 256;                 // don't launch empty blocks
    if (need < 1) need = 1;
    if (NB > need) NB = need;
    if (ws_size >= 4096 + (size_t)slot_bytes) {
        size_t avail = (ws_size - 4096) / slot_bytes;
        if (avail < (size_t)NB) NB = (int)avail;
    } else {
        NB = 1;
    }

    hm_hist<<<NB, 256, 0, stream>>>(src, tgt, ngroups, n, partials);

    hm_tables<<<3, 1024, 0, stream>>>(partials, NB, (float)pixcnt - 1.0f, pxmap);

    int mblocks = (ngroups + 255) / 256;
    if (mblocks > 1024) mblocks = 1024;
    if (mblocks < 1) mblocks = 1;
    hm_map<<<mblocks, 256, 0, stream>>>(src, pxmap, out, ngroups, n);
}

// Round 5
// 93.364 us; speedup vs baseline: 1.4491x; 1.4491x over previous
//
#include <hip/hip_runtime.h>

#define NBINS 256
#define SLOT (6 * NBINS)   // ints per partial-histogram slot

// cs[i] = clip(-1 + i/127, -1, 1) computed exactly as the reference (fp32 ops)
__device__ __forceinline__ float csv(int i) {
    float c = -1.0f + (float)i / 127.0f;
    return fminf(fmaxf(c, -1.0f), 1.0f);
}

__device__ __forceinline__ int binof(float v) {
    v = fminf(fmaxf(v, -1.0f), 1.0f);
    int b = (int)((v + 1.0f) * 128.0f);   // trunc toward zero == astype(int32)
    return min(max(b, 0), NBINS - 1);
}

// ---------------------------------------------------------------------------
// Kernel 1: per-block private histograms -> partials[blockIdx][6][256]
// (non-atomic flush). Each thread handles groups of 12 consecutive elements
// (= 3 float4 loads) so channel indices are compile-time constants.
// Grid must be exactly NB blocks (each owns one partials slot).
// ---------------------------------------------------------------------------
__global__ __launch_bounds__(256) void hm_hist(const float* __restrict__ src,
                                               const float* __restrict__ tgt,
                                               int ngroups, int n,
                                               int* __restrict__ partials) {
    __shared__ int lh[SLOT];
    for (int i = threadIdx.x; i < SLOT; i += blockDim.x) lh[i] = 0;
    __syncthreads();

    const float4* __restrict__ s4 = (const float4*)src;
    const float4* __restrict__ t4 = (const float4*)tgt;
    const int stride = gridDim.x * blockDim.x;
    for (int g = blockIdx.x * blockDim.x + threadIdx.x; g < ngroups; g += stride) {
        int b = g * 3;   // float4 index; covers flat elements 12g .. 12g+11
        float4 s0 = s4[b], s1 = s4[b + 1], s2 = s4[b + 2];
        float4 t0 = t4[b], t1 = t4[b + 1], t2 = t4[b + 2];
        // channels of elements 12g+0..11 are 0,1,2 repeating
        atomicAdd(&lh[0 * NBINS + binof(s0.x)], 1);
        atomicAdd(&lh[1 * NBINS + binof(s0.y)], 1);
        atomicAdd(&lh[2 * NBINS + binof(s0.z)], 1);
        atomicAdd(&lh[0 * NBINS + binof(s0.w)], 1);
        atomicAdd(&lh[1 * NBINS + binof(s1.x)], 1);
        atomicAdd(&lh[2 * NBINS + binof(s1.y)], 1);
        atomicAdd(&lh[0 * NBINS + binof(s1.z)], 1);
        atomicAdd(&lh[1 * NBINS + binof(s1.w)], 1);
        atomicAdd(&lh[2 * NBINS + binof(s2.x)], 1);
        atomicAdd(&lh[0 * NBINS + binof(s2.y)], 1);
        atomicAdd(&lh[1 * NBINS + binof(s2.z)], 1);
        atomicAdd(&lh[2 * NBINS + binof(s2.w)], 1);

        atomicAdd(&lh[3 * NBINS + binof(t0.x)], 1);
        atomicAdd(&lh[4 * NBINS + binof(t0.y)], 1);
        atomicAdd(&lh[5 * NBINS + binof(t0.z)], 1);
        atomicAdd(&lh[3 * NBINS + binof(t0.w)], 1);
        atomicAdd(&lh[4 * NBINS + binof(t1.x)], 1);
        atomicAdd(&lh[5 * NBINS + binof(t1.y)], 1);
        atomicAdd(&lh[3 * NBINS + binof(t1.z)], 1);
        atomicAdd(&lh[4 * NBINS + binof(t1.w)], 1);
        atomicAdd(&lh[5 * NBINS + binof(t2.x)], 1);
        atomicAdd(&lh[3 * NBINS + binof(t2.y)], 1);
        atomicAdd(&lh[4 * NBINS + binof(t2.z)], 1);
        atomicAdd(&lh[5 * NBINS + binof(t2.w)], 1);
    }
    // scalar tail (n not divisible by 12)
    if (blockIdx.x == 0) {
        int base = ngroups * 12;
        int rem = n - base;
        if ((int)threadIdx.x < rem) {
            int j = base + threadIdx.x;
            int c = j % 3;
            atomicAdd(&lh[c * NBINS + binof(src[j])], 1);
            atomicAdd(&lh[(3 + c) * NBINS + binof(tgt[j])], 1);
        }
    }
    __syncthreads();

    int* dst = partials + blockIdx.x * SLOT;
    for (int i = threadIdx.x; i < SLOT; i += blockDim.x) dst[i] = lh[i];
}

// ---------------------------------------------------------------------------
// Kernel 1.5: parallel level-1 reduction of 256 partial slots -> 16 slots
// (result for group k lands in slot 16*k). Block b: h = b/16 (histogram 0..5),
// k = b%16 (group). Each thread sums 16 independent loads (fully pipelined;
// 24576 threads total -- this is what keeps it latency-hidden, cf. R2/R4).
// ---------------------------------------------------------------------------
__global__ void hm_reduce(int* __restrict__ partials) {
    int h = blockIdx.x >> 4;    // 0..5
    int k = blockIdx.x & 15;    // 0..15
    int t = threadIdx.x;
    int base = (k * 16) * SLOT + h * NBINS + t;
    int s = 0;
    #pragma unroll
    for (int j = 0; j < 16; j++) s += partials[base + j * SLOT];
    partials[base] = s;
}

// ---------------------------------------------------------------------------
// Kernel 2: 3 blocks (one per channel) x 1024 threads. 4 thread-groups of 256
// reduce nslots slots (spaced `step` apart) in parallel, LDS-combine, then
// scan -> cdfs/cdft -> pxmap = _interpolate(cdftgt, cs, cdfsrc).
// With the two-level reduce, nslots=16 -> only 4 serial loads per thread.
// ---------------------------------------------------------------------------
__global__ __launch_bounds__(1024) void hm_tables(const int* __restrict__ partials,
                                                  int nslots, int step,
                                                  float pixcnt_m1,
                                                  float* __restrict__ pxmap) {
    const int c = blockIdx.x;
    const int t = threadIdx.x;
    const int grp = t >> 8;     // 0..3
    const int bin = t & 255;

    __shared__ int red[8][NBINS];          // [grp] src, [4+grp] tgt
    __shared__ int ss[NBINS], st[NBINS];
    __shared__ float cdfs[NBINS], cdft[NBINS];

    int as = 0, at = 0;
    for (int b = grp; b < nslots; b += 4) {
        const int* p = partials + (b * step) * SLOT;
        as += p[c * NBINS + bin];
        at += p[(3 + c) * NBINS + bin];
    }
    red[grp][bin] = as;
    red[4 + grp][bin] = at;
    __syncthreads();

    if (t < NBINS) {
        ss[t] = red[0][t] + red[1][t] + red[2][t] + red[3][t];
        st[t] = red[4][t] + red[5][t] + red[6][t] + red[7][t];
    }
    __syncthreads();

    // Hillis-Steele inclusive scan (256 active lanes; all threads hit barriers)
    for (int off = 1; off < NBINS; off <<= 1) {
        int a = 0, b = 0;
        if (t < NBINS && t >= off) { a = ss[t - off]; b = st[t - off]; }
        __syncthreads();
        if (t < NBINS && t >= off) { ss[t] += a; st[t] += b; }
        __syncthreads();
    }

    if (t < NBINS) {
        // cdf nondecreasing -> min = cdf[0]; exact ref op order
        int mins = ss[0];
        int mint = st[0];
        cdfs[t] = (float)(ss[t] - mins) * 2.0f / pixcnt_m1 - 1.0f;
        cdft[t] = (float)(st[t] - mint) * 2.0f / pixcnt_m1 - 1.0f;
    }
    __syncthreads();

    if (t < NBINS) {
        // pxmap[t] = _interpolate(dx=cdftgt, dy=cs, x=cdfsrc[t]); first-min argmin
        float x = cdfs[t];
        int ind1 = 0;
        float best = fabsf(cdft[0] - x);
        for (int i = 1; i < NBINS; i++) {
            float d = fabsf(cdft[i] - x);
            if (d < best) { best = d; ind1 = i; }
        }
        int ind0 = max(ind1 - 1, 0);
        float x0 = cdft[ind0], x1 = cdft[ind1];
        float y0 = csv(ind0),  y1 = csv(ind1);
        float denom = x1 - x0;
        float safe = (denom == 0.0f) ? 1.0f : denom;
        float interp = y0 + (y1 - y0) * (x - x0) / safe;

        float r;
        if (x <= cdft[0])              r = csv(0);
        else if (x >= cdft[NBINS - 1]) r = csv(NBINS - 1);
        else                           r = interp;

        pxmap[c * NBINS + t] = r;
    }
}

// ---------------------------------------------------------------------------
// Kernel 3: mapped = _interpolate(dx=cs, dy=pxmap[c], x=src). 12-elem groups,
// compile-time channels, cs table in LDS (no fp32 divides for grid values).
// ---------------------------------------------------------------------------
__device__ __forceinline__ float map_one(float x, const float* __restrict__ y,
                                         const float* __restrict__ cs) {
    if (x <= -1.0f) return y[0];
    if (x >= 1.0f)  return y[NBINS - 1];
    float kf = (x + 1.0f) * 127.0f;
    int k = (int)(kf + 0.5f);
    int lo = max(k - 1, 0);
    int hi = min(k + 1, NBINS - 1);
    int ind1 = lo;
    float best = fabsf(cs[lo] - x);
    for (int j = lo + 1; j <= hi; j++) {
        float d = fabsf(cs[j] - x);
        if (d < best) { best = d; ind1 = j; }   // strict < => first-min
    }
    int ind0 = max(ind1 - 1, 0);
    float x0 = cs[ind0], x1 = cs[ind1];
    float y0 = y[ind0],  y1 = y[ind1];
    float denom = x1 - x0;
    float safe = (denom == 0.0f) ? 1.0f : denom;
    return y0 + (y1 - y0) * (x - x0) / safe;
}

__global__ __launch_bounds__(256) void hm_map(const float* __restrict__ src,
                                              const float* __restrict__ pxmap,
                                              float* __restrict__ out,
                                              int ngroups, int n) {
    __shared__ float pm[3 * NBINS];
    __shared__ float cs[NBINS];
    for (int i = threadIdx.x; i < 3 * NBINS; i += blockDim.x) pm[i] = pxmap[i];
    for (int i = threadIdx.x; i < NBINS; i += blockDim.x) cs[i] = csv(i);
    __syncthreads();

    const float4* __restrict__ s4 = (const float4*)src;
    float4* __restrict__ o4 = (float4*)out;
    const int stride = gridDim.x * blockDim.x;
    for (int g = blockIdx.x * blockDim.x + threadIdx.x; g < ngroups; g += stride) {
        int b = g * 3;
        float4 s0 = s4[b], s1 = s4[b + 1], s2 = s4[b + 2];
        float4 r0, r1, r2;
        r0.x = map_one(s0.x, &pm[0 * NBINS], cs);
        r0.y = map_one(s0.y, &pm[1 * NBINS], cs);
        r0.z = map_one(s0.z, &pm[2 * NBINS], cs);
        r0.w = map_one(s0.w, &pm[0 * NBINS], cs);
        r1.x = map_one(s1.x, &pm[1 * NBINS], cs);
        r1.y = map_one(s1.y, &pm[2 * NBINS], cs);
        r1.z = map_one(s1.z, &pm[0 * NBINS], cs);
        r1.w = map_one(s1.w, &pm[1 * NBINS], cs);
        r2.x = map_one(s2.x, &pm[2 * NBINS], cs);
        r2.y = map_one(s2.y, &pm[0 * NBINS], cs);
        r2.z = map_one(s2.z, &pm[1 * NBINS], cs);
        r2.w = map_one(s2.w, &pm[2 * NBINS], cs);
        o4[b] = r0; o4[b + 1] = r1; o4[b + 2] = r2;
    }
    // scalar tail
    if (blockIdx.x == 0) {
        int base = ngroups * 12;
        int rem = n - base;
        if ((int)threadIdx.x < rem) {
            int j = base + threadIdx.x;
            int c = j % 3;
            out[j] = map_one(src[j], &pm[c * NBINS], cs);
        }
    }
}

extern "C" void kernel_launch(void* const* d_in, const int* in_sizes, int n_in,
                              void* d_out, int out_size, void* d_ws, size_t ws_size,
                              hipStream_t stream) {
    const float* src = (const float*)d_in[0];
    const float* tgt = (const float*)d_in[1];
    float* out = (float*)d_out;

    const int n = in_sizes[0];       // H*W*3
    const int ngroups = n / 12;      // 12-element (3x float4) groups
    const int pixcnt = n / 3;        // H*W

    // ws layout: [0, 4096): pxmap (3*256 floats); [4096, ...): partials
    float* pxmap    = (float*)d_ws;
    int*   partials = (int*)((char*)d_ws + 4096);

    const int slot_bytes = SLOT * (int)sizeof(int);   // 6 KiB per slot
    int NB = 256;                    // 256 slots: enough blocks for HBM BW,
                                     // small enough for the 2-level reduce
    int need = (ngroups + 255) / 256;
    if (need < 1) need = 1;
    if (NB > need) NB = need;
    if (ws_size >= 4096 + (size_t)slot_bytes) {
        size_t avail = (ws_size - 4096) / slot_bytes;
        if (avail < (size_t)NB) NB = (int)avail;
    } else {
        NB = 1;
    }

    hm_hist<<<NB, 256, 0, stream>>>(src, tgt, ngroups, n, partials);

    if (NB == 256) {
        // level-1 reduce: 256 slots -> 16 slots (indices 0,16,...,240)
        hm_reduce<<<96, NBINS, 0, stream>>>(partials);
        hm_tables<<<3, 1024, 0, stream>>>(partials, 16, 16,
                                          (float)pixcnt - 1.0f, pxmap);
    } else {
        hm_tables<<<3, 1024, 0, stream>>>(partials, NB, 1,
                                          (float)pixcnt - 1.0f, pxmap);
    }

    int mblocks = (ngroups + 255) / 256;
    if (mblocks > 1024) mblocks = 1024;
    if (mblocks < 1) mblocks = 1;
    hm_map<<<mblocks, 256, 0, stream>>>(src, pxmap, out, ngroups, n);
}